// Round 8
// baseline (886.818 us; speedup 1.0000x reference)
//
#include <hip/hip_runtime.h>

// WindowAttention (Swin-style) on gfx950 — R11.
// R11 changes vs R10:
//   * conv_f32_bf16 pass DELETED. gemm_qkv reads f32 x directly: A-staging is
//     reg-staged (f32 global -> v_cvt_pk_bf16_f32 -> ds_write_b128, contiguous
//     per-wave LDS writes, layout byte-identical to the old As). B path keeps
//     global_load_lds. Saves ~308MB of conv traffic + a serial dispatch.
//   * xbf workspace region now used ONLY as attn_out.
//   * attn2 / gemm_bt / build_combined unchanged from R10.
// ws layout (bytes): unchanged.

typedef unsigned short u16;
typedef __attribute__((ext_vector_type(8))) short short8;
typedef __attribute__((ext_vector_type(4))) float floatx4;
typedef __attribute__((ext_vector_type(4))) unsigned u32x4;

#define B_WIN 2048
#define SEQ 49
#define DIM 512
#define NHEAD 16
#define HD 32
#define MROWS (B_WIN * SEQ)          // 100352
#define QTOT 51380224u               // 2048*16*49*32 elems (one Q or K plane set)
#define VOFF 102760448u              // elem offset of Vt planes ( = 2*QTOT)

__device__ __forceinline__ u16 f2bf(float x) {
    unsigned u = __float_as_uint(x);
    u += 0x7fffu + ((u >> 16) & 1u);   // RNE
    return (u16)(u >> 16);
}

__device__ __forceinline__ unsigned cvt_pk_bf16(float lo, float hi) {
    unsigned r;
    asm("v_cvt_pk_bf16_f32 %0, %1, %2" : "=v"(r) : "v"(lo), "v"(hi));
    return r;
}

__device__ __forceinline__ void async_ld16(const void* g, void* l) {
    __builtin_amdgcn_global_load_lds(
        (const __attribute__((address_space(1))) void*)g,
        (__attribute__((address_space(3))) void*)l, 16, 0, 0);
}

// in: [512][Cn] f32 (k-major). out: [Cn][512] bf16 (n-major).
__global__ void transpose_conv(const float* __restrict__ in, u16* __restrict__ out, int Cn) {
    int id = blockIdx.x * 256 + threadIdx.x;
    if (id >= Cn * 512) return;
    int k = id & 511;
    int n = id >> 9;
    out[id] = f2bf(in[(size_t)k * Cn + n]);
}

// Natural-layout padded combined table, pre-scaled by log2(e):
// cmb[w][h][row 0..48][col 0..63]:
//   col < 49 : (bias_table[rel_idx[row*49+col]][h] + mask[w][row*49+col]) * log2e
//   col >= 49: -1e30 (softmax pad)
__global__ void build_combined(const float* __restrict__ mask, const float* __restrict__ bias_table,
                               const int* __restrict__ rel_idx, float* __restrict__ cmb) {
    const float LOG2E = 1.4426950408889634f;
    int id = blockIdx.x * 256 + threadIdx.x;    // 64*16*49*64 = 3,211,264
    if (id >= 64 * 16 * 49 * 64) return;
    int col = id & 63;
    int t   = id >> 6;
    int row = t % 49;
    int wh  = t / 49;
    int h = wh & 15, w = wh >> 4;
    float v = -1.0e30f;
    if (col < 49) {
        int ij = row * 49 + col;
        v = (bias_table[rel_idx[ij] * NHEAD + h] + mask[(size_t)w * 2401 + ij]) * LOG2E;
    }
    cmb[id] = v;
}

// zero V^T pad region: elems s in [48,64) per (bh, d). gemm_qkv later rewrites s=48.
__global__ void zero_vpad(u16* __restrict__ qkvp) {
    int id = blockIdx.x * 256 + threadIdx.x;     // 2048*16*32 = 1,048,576
    if (id >= 2048 * 16 * 32) return;
    uint4 z = {0u, 0u, 0u, 0u};
    u16* p = qkvp + VOFF + (size_t)id * 64 + 48; // byte offset 96: 16B aligned
    *(uint4*)p = z;                               // elems 48..55
    *((uint4*)p + 1) = z;                         // elems 56..63
}

// ---------- GEMM1: qkv = x(f32) @ qkv_w + b, scattered to per-head planes ----
// A staged f32->bf16 in-flight (cvt_pk + ds_write_b128); B via global_load_lds.
__global__ __launch_bounds__(256, 2)
void gemm_qkv(const float* __restrict__ A, const u16* __restrict__ Bt,
              const float* __restrict__ bias, u16* __restrict__ qkvp) {
    const int K = 512;
    const int tid  = threadIdx.x;
    const int lane = tid & 63, wave = tid >> 6;
    const int quad = lane >> 4, l16 = lane & 15;
    const int wr = wave >> 1, wc = wave & 1;

    // XCD-bijective swizzle: 9408 blocks = 8 * 1176.
    const int flat = blockIdx.y * 12 + blockIdx.x;
    const int swz  = (flat & 7) * 1176 + (flat >> 3);
    const int bx = swz % 12;
    const int by = swz / 12;
    const int m0 = by * 128, n0 = bx * 128;

    // K-loop: As = smem[0..4095], Bs = smem[4096..8191] (each 128x32 u16).
    // Epilogue: whole buffer reused as 128x136 bf16 stage.
    __shared__ u16 smem[128 * 136];
    u16* As = smem;
    u16* Bs = smem + 4096;

    // B staging (global_load_lds, as before)
    const int f0 = (wave * 2 + 0) * 512 + lane * 8;
    const int f1 = (wave * 2 + 1) * 512 + lane * 8;
    const int r0 = f0 >> 5, c0 = f0 & 31;
    const int r1 = f1 >> 5, c1 = f1 & 31;
    const u16* Bb = Bt + (size_t)n0 * K;

    // A staging (reg-staged f32->bf16): thread covers rows ar0, ar0+64,
    // cols ac..ac+8 of the 128x32 tile. LDS write byte = wave*1024 + lane*16
    // (+32KB half) -> contiguous per wave, conflict-free.
    const int ar0 = tid >> 2;            // 0..63
    const int ar1 = ar0 + 64;
    const int ac  = (tid & 3) * 8;       // 0/8/16/24
    const float* Af = A + (size_t)m0 * K;

    floatx4 acc[4][4] = {};

    for (int kt = 0; kt < K; kt += 32) {
        // A: 2 rows x 8 f32 each (2x dwordx4 per row), coalesced per 4 lanes
        const float* a0p = Af + (size_t)ar0 * K + kt + ac;
        const float* a1p = Af + (size_t)ar1 * K + kt + ac;
        float4 av0 = *(const float4*)(a0p);
        float4 av1 = *(const float4*)(a0p + 4);
        float4 av2 = *(const float4*)(a1p);
        float4 av3 = *(const float4*)(a1p + 4);
        // B: async global->LDS
        async_ld16(Bb + (size_t)r0 * K + kt + c0, &Bs[f0]);
        async_ld16(Bb + (size_t)r1 * K + kt + c1, &Bs[f1]);
        // A: convert + LDS write (compiler inserts the vmcnt waits)
        u32x4 w0, w1;
        w0[0] = cvt_pk_bf16(av0.x, av0.y); w0[1] = cvt_pk_bf16(av0.z, av0.w);
        w0[2] = cvt_pk_bf16(av1.x, av1.y); w0[3] = cvt_pk_bf16(av1.z, av1.w);
        w1[0] = cvt_pk_bf16(av2.x, av2.y); w1[1] = cvt_pk_bf16(av2.z, av2.w);
        w1[2] = cvt_pk_bf16(av3.x, av3.y); w1[3] = cvt_pk_bf16(av3.z, av3.w);
        *(u32x4*)&As[ar0 * 32 + ac] = w0;
        *(u32x4*)&As[ar1 * 32 + ac] = w1;
        __syncthreads();
        short8 af[4], bf[4];
#pragma unroll
        for (int i = 0; i < 4; ++i)
            af[i] = *(const short8*)&As[(wr * 64 + i * 16 + l16) * 32 + quad * 8];
#pragma unroll
        for (int j = 0; j < 4; ++j)
            bf[j] = *(const short8*)&Bs[(wc * 64 + j * 16 + l16) * 32 + quad * 8];
#pragma unroll
        for (int i = 0; i < 4; ++i)
#pragma unroll
            for (int j = 0; j < 4; ++j)
                acc[i][j] = __builtin_amdgcn_mfma_f32_16x16x32_bf16(af[i], bf[j], acc[i][j], 0, 0, 0);
        __syncthreads();
    }

    // ---- epilogue phase A: acc (+bias) -> bf16 into padded LDS stage ----
#pragma unroll
    for (int j = 0; j < 4; ++j) {
        const int col = wc * 64 + j * 16 + l16;
        const float bv = bias[n0 + col];
#pragma unroll
        for (int i = 0; i < 4; ++i)
#pragma unroll
            for (int r = 0; r < 4; ++r) {
                const int row = wr * 64 + i * 16 + quad * 4 + r;
                smem[row * 136 + col] = f2bf(acc[i][j][r] + bv);
            }
    }
    __syncthreads();

    // ---- epilogue phase B: cooperative coalesced writeout ----
    if (n0 < 1024) {
        // Q or K planes: [bh][49][32]; 16B chunks, 64B-line aligned.
        const int c   = n0 >> 9;
        const int hh0 = (n0 & 511) >> 5;
        u16* base = qkvp + (size_t)c * QTOT;
#pragma unroll
        for (int it = 0; it < 8; ++it) {
            const int idx  = it * 256 + tid;      // 0..2047
            const int row  = idx >> 4;
            const int hb   = (idx >> 2) & 3;
            const int part = idx & 3;
            short8 v = *(const short8*)&smem[row * 136 + hb * 32 + part * 8];
            const int rg = m0 + row;
            const int b2 = (int)((unsigned)rg / 49u);
            const int s  = rg - b2 * 49;
            *(short8*)(base + (size_t)(b2 * 16 + hh0 + hb) * 1568 + s * 32 + part * 8) = v;
        }
    } else {
        // V^T planes: [bh][32 d][64 s]; lanes along s (contiguous dst runs).
        const int hh0 = (n0 - 1024) >> 5;
        u16* base = qkvp + VOFF;
#pragma unroll 16
        for (int it = 0; it < 64; ++it) {
            const int idx = it * 256 + tid;       // 0..16383
            const int col = idx >> 7;             // 0..127 (tile col = head*32+d)
            const int row = idx & 127;
            const u16 v = smem[row * 136 + col];
            const int rg = m0 + row;
            const int b2 = (int)((unsigned)rg / 49u);
            const int s  = rg - b2 * 49;
            const int hh = hh0 + (col >> 5);
            const int d  = col & 31;
            base[(size_t)(b2 * 16 + hh) * 2048 + d * 64 + s] = v;
        }
    }
}

// ---------- GEMM: C[M][N] = A[M][K](bf16) * Bt[N][K]^T + bias (f32 out) ----------
__global__ __launch_bounds__(256, 2)
void gemm_bt(const u16* __restrict__ A, const u16* __restrict__ Bt,
             const float* __restrict__ bias, float* __restrict__ Cout,
             int M, int N, int K) {
    const int tid  = threadIdx.x;
    const int lane = tid & 63, wave = tid >> 6;
    const int quad = lane >> 4, l16 = lane & 15;
    const int wr = wave >> 1, wc = wave & 1;

    // XCD-bijective swizzle (applied when grid divides by 8).
    const int nbx = gridDim.x, nby = gridDim.y;
    const int total = nbx * nby;
    const int flat = blockIdx.y * nbx + blockIdx.x;
    const int swz = ((total & 7) == 0) ? ((flat & 7) * (total >> 3) + (flat >> 3)) : flat;
    const int bx = swz % nbx;
    const int by = swz / nbx;
    const int m0 = by * 128, n0 = bx * 128;

    __shared__ u16 As[128 * 32];
    __shared__ u16 Bs[128 * 32];

    const int f0 = (wave * 2 + 0) * 512 + lane * 8;
    const int f1 = (wave * 2 + 1) * 512 + lane * 8;
    const int r0 = f0 >> 5, c0 = f0 & 31;
    const int r1 = f1 >> 5, c1 = f1 & 31;
    const u16* Ab = A + (size_t)m0 * K;
    const u16* Bb = Bt + (size_t)n0 * K;

    floatx4 acc[4][4] = {};

    for (int kt = 0; kt < K; kt += 32) {
        async_ld16(Ab + (size_t)r0 * K + kt + c0, &As[f0]);
        async_ld16(Ab + (size_t)r1 * K + kt + c1, &As[f1]);
        async_ld16(Bb + (size_t)r0 * K + kt + c0, &Bs[f0]);
        async_ld16(Bb + (size_t)r1 * K + kt + c1, &Bs[f1]);
        __syncthreads();
        short8 af[4], bf[4];
#pragma unroll
        for (int i = 0; i < 4; ++i)
            af[i] = *(const short8*)&As[(wr * 64 + i * 16 + l16) * 32 + quad * 8];
#pragma unroll
        for (int j = 0; j < 4; ++j)
            bf[j] = *(const short8*)&Bs[(wc * 64 + j * 16 + l16) * 32 + quad * 8];
#pragma unroll
        for (int i = 0; i < 4; ++i)
#pragma unroll
            for (int j = 0; j < 4; ++j)
                acc[i][j] = __builtin_amdgcn_mfma_f32_16x16x32_bf16(af[i], bf[j], acc[i][j], 0, 0, 0);
        __syncthreads();
    }

#pragma unroll
    for (int i = 0; i < 4; ++i) {
#pragma unroll
        for (int j = 0; j < 4; ++j) {
            int col = n0 + wc * 64 + j * 16 + l16;
            float bv = bias[col];
#pragma unroll
            for (int r = 0; r < 4; ++r) {
                int row = m0 + wr * 64 + i * 16 + quad * 4 + r;
                Cout[(size_t)row * N + col] = acc[i][j][r] + bv;
            }
        }
    }
}

// ---------- attention: swapped QK^T, in-register softmax, no LDS ----------
__global__ __launch_bounds__(64, 4)
void attn2(const u16* __restrict__ qkvp, const float* __restrict__ cmbp,
           u16* __restrict__ out) {
    const int lane = threadIdx.x;
    const int quad = lane >> 4, l16 = lane & 15;
    const int p0 = blockIdx.x * 2;                 // pairs p0, p0+1 (same b, h0 even)
    const int b  = p0 >> 4, h0 = p0 & 15;

    const u16* qb0 = qkvp + (size_t)p0 * 1568;
    const u16* kb0 = qb0 + QTOT;
    const u16* vb0 = qkvp + VOFF + (size_t)p0 * 2048;   // V^T [32][64]
    const float* cb0 = cmbp + (size_t)((b & 63) * 16 + h0) * 49 * 64;

    u16* op0 = out + (size_t)b * SEQ * DIM + h0 * HD;
    u16* op1 = op0 + HD;

    const float scale2 = 0.2550348754f;            // 32^-0.5 * log2(e)

    // packed bf16 outputs: ob[pair][j][n][w] (w: rows {0,1} / {2,3})
    unsigned ob0[4][2][2], ob1[4][2][2];

    auto run_pair = [&](const u16* qb, const u16* kb, const u16* vb,
                        const float* cbp, unsigned (&ob)[4][2][2]) {
        // K as MFMA A-operand: kf[i] = K rows i*16+l16 (clamped), d = quad*8..+8
        short8 kf[4];
#pragma unroll
        for (int i = 0; i < 4; ++i) {
            int rk = i * 16 + l16; if (rk > 48) rk = 48;
            kf[i] = *(const short8*)(kb + rk * 32 + quad * 8);
        }
        // V^T as B-operand: vf[kt][n] = d-row n*16+l16, keys kt*32+quad*8..+8
        short8 vf[2][2];
#pragma unroll
        for (int kt = 0; kt < 2; ++kt)
#pragma unroll
            for (int n = 0; n < 2; ++n)
                vf[kt][n] = *(const short8*)(vb + (n * 16 + l16) * 64 + kt * 32 + quad * 8);

#pragma unroll
        for (int j = 0; j < 4; ++j) {
            const int q  = j * 16 + l16;
            const int rc = q < 49 ? q : 48;        // clamp (pad queries discarded)
            const short8 qf = *(const short8*)(qb + rc * 32 + quad * 8);

            // S^T tiles: accT[i][r] = S[q][k = i*16+quad*4+r]
            floatx4 accT[4] = {};
#pragma unroll
            for (int i = 0; i < 4; ++i)
                accT[i] = __builtin_amdgcn_mfma_f32_16x16x32_bf16(kf[i], qf, accT[i], 0, 0, 0);

            // logits + row max (in-lane 16 values, then 2 shuffles across quads)
            float x[4][4];
            float m = -3.0e38f;
#pragma unroll
            for (int i = 0; i < 4; ++i) {
                float4 c4 = *(const float4*)(cbp + rc * 64 + i * 16 + quad * 4);
                x[i][0] = accT[i][0] * scale2 + c4.x;
                x[i][1] = accT[i][1] * scale2 + c4.y;
                x[i][2] = accT[i][2] * scale2 + c4.z;
                x[i][3] = accT[i][3] * scale2 + c4.w;
                m = fmaxf(m, fmaxf(fmaxf(x[i][0], x[i][1]), fmaxf(x[i][2], x[i][3])));
            }
            m = fmaxf(m, __shfl_xor(m, 16));
            m = fmaxf(m, __shfl_xor(m, 32));

            float s = 0.f;
#pragma unroll
            for (int i = 0; i < 4; ++i)
#pragma unroll
                for (int r = 0; r < 4; ++r) {
                    float e = __builtin_amdgcn_exp2f(x[i][r] - m);
                    x[i][r] = e; s += e;
                }
            s += __shfl_xor(s, 16);
            s += __shfl_xor(s, 32);
            const float inv = __builtin_amdgcn_rcpf(s);

            // normalized P -> packed bf16: pk[i][w] = P[q][k=i*16+quad*4+{2w,2w+1}]
            unsigned pk[4][2];
#pragma unroll
            for (int i = 0; i < 4; ++i) {
                pk[i][0] = (unsigned)f2bf(x[i][0] * inv) | ((unsigned)f2bf(x[i][1] * inv) << 16);
                pk[i][1] = (unsigned)f2bf(x[i][2] * inv) | ((unsigned)f2bf(x[i][3] * inv) << 16);
            }

            // PV: assemble A-frags (row q, k = kt*32+quad*8+t) by cross-quad shfl
            floatx4 accO[2] = {};
#pragma unroll
            for (int kt = 0; kt < 2; ++kt) {
                u32x4 w;
#pragma unroll
                for (int W = 0; W < 4; ++W) {
                    const int src = (((quad & 1) * 2 + (W >> 1)) << 4) + l16;
                    const unsigned lo = (unsigned)__shfl((int)pk[2 * kt + 0][W & 1], src);
                    const unsigned hi = (unsigned)__shfl((int)pk[2 * kt + 1][W & 1], src);
                    w[W] = (quad & 2) ? hi : lo;
                }
                const short8 pa = __builtin_bit_cast(short8, w);
#pragma unroll
                for (int n = 0; n < 2; ++n)
                    accO[n] = __builtin_amdgcn_mfma_f32_16x16x32_bf16(pa, vf[kt][n], accO[n], 0, 0, 0);
            }
            // pack output tile j: O[q=j*16+quad*4+r][d=n*16+l16]
#pragma unroll
            for (int n = 0; n < 2; ++n) {
                ob[j][n][0] = (unsigned)f2bf(accO[n][0]) | ((unsigned)f2bf(accO[n][1]) << 16);
                ob[j][n][1] = (unsigned)f2bf(accO[n][2]) | ((unsigned)f2bf(accO[n][3]) << 16);
            }
        }
    };

    run_pair(qb0,        kb0,        vb0,        cb0,           ob0);
    run_pair(qb0 + 1568, kb0 + 1568, vb0 + 2048, cb0 + 49 * 64, ob1);

    // merged store: per row, heads h0 and h0+1 written back-to-back
#pragma unroll
    for (int j = 0; j < 4; ++j)
#pragma unroll
        for (int r = 0; r < 4; ++r) {
            const int row = j * 16 + quad * 4 + r;
            if (row < SEQ) {
#pragma unroll
                for (int n = 0; n < 2; ++n) {
                    const unsigned w = ob0[j][n][r >> 1];
                    op0[(size_t)row * DIM + n * 16 + l16] =
                        (u16)((r & 1) ? (w >> 16) : (w & 0xffffu));
                }
#pragma unroll
                for (int n = 0; n < 2; ++n) {
                    const unsigned w = ob1[j][n][r >> 1];
                    op1[(size_t)row * DIM + n * 16 + l16] =
                        (u16)((r & 1) ? (w >> 16) : (w & 0xffffu));
                }
            }
        }
}

extern "C" void kernel_launch(void* const* d_in, const int* in_sizes, int n_in,
                              void* d_out, int out_size, void* d_ws, size_t ws_size,
                              hipStream_t stream) {
    const float* x         = (const float*)d_in[0];
    const float* mask      = (const float*)d_in[1];
    const float* qkv_w     = (const float*)d_in[2];
    const float* qkv_b     = (const float*)d_in[3];
    const float* proj_w    = (const float*)d_in[4];
    const float* proj_b    = (const float*)d_in[5];
    const float* bias_tab  = (const float*)d_in[6];
    const int*   rel_idx   = (const int*)d_in[7];
    float* out = (float*)d_out;

    char* ws = (char*)d_ws;
    u16*   xbf     = (u16*)(ws + 0);               // attn_out only (conv removed)
    u16*   qkvp    = (u16*)(ws + 102760448);
    u16*   wqkv_t  = (u16*)(ws + 452333568);
    u16*   wproj_t = (u16*)(ws + 453906432);
    // natural-layout padded combined table lives in d_out (scratch until gemm_bt):
    float* cmb     = out;                          // 64*16*49*64 f32 = 12.8 MB

    // weight transposes
    transpose_conv<<<3072, 256, 0, stream>>>(qkv_w, wqkv_t, 1536);
    transpose_conv<<<1024, 256, 0, stream>>>(proj_w, wproj_t, 512);
    // natural padded combined bias+mask table (x log2e) -> d_out scratch
    build_combined<<<12544, 256, 0, stream>>>(mask, bias_tab, rel_idx, cmb);
    // zero V^T pad rows (s in [48,64)) before gemm_qkv rewrites s=48
    zero_vpad<<<4096, 256, 0, stream>>>(qkvp);
    // qkv GEMM, f32 A consumed directly (conversion fused into staging)
    gemm_qkv<<<dim3(12, 784), 256, 0, stream>>>(x, wqkv_t, qkv_b, qkvp);
    // attention (2 pairs per wave, register softmax) -> attn_out (xbf)
    attn2<<<B_WIN * NHEAD / 2, 64, 0, stream>>>(qkvp, cmb, xbf);
    // out = attn @ proj_w + proj_b (overwrites the cmb scratch)
    gemm_bt<<<dim3(4, 784), 256, 0, stream>>>(xbf, wproj_t, proj_b, out,
                                              MROWS, 512, 512);
}